// Round 1
// baseline (294.091 us; speedup 1.0000x reference)
//
#include <hip/hip_runtime.h>
#include <hip/hip_bf16.h>

#define BATCH 2048
#define KDIM  100000
#define DIM   64
#define KSTEP 64
#define NSTEPS ((KDIM + KSTEP - 1) / KSTEP)   // 1563 (last step has 32 valid k)
#define KPARTS 16
#define ROWS_PER_BLOCK 64                     // 4 waves x 16 rows
#define LDS_PAD 72                            // 64 + 8 ushorts -> 144B col stride

typedef __attribute__((ext_vector_type(8))) short  short8;
typedef __attribute__((ext_vector_type(4))) float  f32x4;

__device__ __forceinline__ unsigned short f2bf(float f) {
    union { float f; unsigned int u; } v; v.f = f;
    unsigned int u = v.u;
    u += 0x7FFFu + ((u >> 16) & 1u);          // round-to-nearest-even
    return (unsigned short)(u >> 16);
}

__global__ __launch_bounds__(256, 2)
void hashemb_matmul(const float* __restrict__ inp,
                    const float* __restrict__ emb,
                    float* __restrict__ out_acc,
                    float* __restrict__ row_sum) {
    // emb tile transposed: ldsT[col][k'] , col stride 144B (2-way max on b128 reads)
    __shared__ __align__(16) unsigned short ldsT[DIM][LDS_PAD];

    const int tid  = threadIdx.x;
    const int lane = tid & 63;
    const int wid  = tid >> 6;                 // wave 0..3
    const int rb   = blockIdx.x;               // row block 0..31
    const int kp   = blockIdx.y;               // k part 0..15

    const int rowbase = rb * ROWS_PER_BLOCK + wid * 16;
    const int arow    = rowbase + (lane & 15);
    const int kgrp    = lane >> 4;             // 0..3

    // staging assignment: thread t handles emb column sc, k' in [sr0, sr0+16)
    const int sc  = tid & 63;
    const int sr0 = (tid >> 6) * 16;

    f32x4 acc[4];
    #pragma unroll
    for (int t = 0; t < 4; ++t) acc[t] = (f32x4)0.0f;
    float lsum = 0.0f;

    const float* arowp = inp + (size_t)arow * KDIM;

    for (int s = kp; s < NSTEPS; s += KPARTS) {
        const int k0 = s * KSTEP;

        // ---- stage emb[k0 : k0+64][0:64] -> LDS transposed bf16 ----
        float sv[16];
        #pragma unroll
        for (int i = 0; i < 16; ++i) {
            const int kk = k0 + sr0 + i;
            sv[i] = (kk < KDIM) ? emb[(size_t)kk * DIM + sc] : 0.0f;
        }
        __syncthreads();                       // prior iter's LDS reads done
        {
            short8 w0, w1;
            #pragma unroll
            for (int i = 0; i < 8; ++i) {
                w0[i] = (short)f2bf(sv[i]);
                w1[i] = (short)f2bf(sv[8 + i]);
            }
            *(short8*)&ldsT[sc][sr0]     = w0;
            *(short8*)&ldsT[sc][sr0 + 8] = w1;
        }
        __syncthreads();

        // ---- compute: 2 MFMA k-halves of 32 ----
        #pragma unroll
        for (int h = 0; h < 2; ++h) {
            const int kh = k0 + h * 32;        // wave-uniform guard; KDIM % 32 == 0
            if (kh < KDIM) {
                const int kb = kh + kgrp * 8;
                f32x4 a0 = *(const f32x4*)(arowp + kb);
                f32x4 a1 = *(const f32x4*)(arowp + kb + 4);
                lsum += a0[0] + a0[1] + a0[2] + a0[3]
                      + a1[0] + a1[1] + a1[2] + a1[3];
                short8 af;
                #pragma unroll
                for (int j = 0; j < 4; ++j) {
                    af[j]     = (short)f2bf(a0[j]);
                    af[4 + j] = (short)f2bf(a1[j]);
                }
                #pragma unroll
                for (int t = 0; t < 4; ++t) {
                    const short8 bf = *(const short8*)&ldsT[t * 16 + (lane & 15)][h * 32 + kgrp * 8];
                    acc[t] = __builtin_amdgcn_mfma_f32_16x16x32_bf16(af, bf, acc[t], 0, 0, 0);
                }
            }
        }
    }

    // ---- row-sum partial: reduce over the 4 k-groups ----
    lsum += __shfl_xor(lsum, 16, 64);
    lsum += __shfl_xor(lsum, 32, 64);
    if (lane < 16) atomicAdd(&row_sum[rowbase + lane], lsum);

    // ---- matmul partial: C/D layout col = lane&15, row = (lane>>4)*4 + j ----
    #pragma unroll
    for (int t = 0; t < 4; ++t) {
        const int col = t * 16 + (lane & 15);
        #pragma unroll
        for (int j = 0; j < 4; ++j) {
            const int row = rowbase + kgrp * 4 + j;
            atomicAdd(&out_acc[row * DIM + col], acc[t][j]);
        }
    }
}

__global__ __launch_bounds__(256)
void hashemb_finalize(float* __restrict__ out, const float* __restrict__ row_sum) {
    const int idx = blockIdx.x * blockDim.x + threadIdx.x;
    if (idx < BATCH * DIM) {
        const float s = row_sum[idx >> 6];
        const float o = out[idx];
        out[idx] = (s > 0.0f) ? (o / s) : 0.0f;
    }
}

extern "C" void kernel_launch(void* const* d_in, const int* in_sizes, int n_in,
                              void* d_out, int out_size, void* d_ws, size_t ws_size,
                              hipStream_t stream) {
    const float* inp = (const float*)d_in[0];
    const float* emb = (const float*)d_in[1];
    float* out = (float*)d_out;
    float* rs  = (float*)d_ws;

    // harness poisons d_out/d_ws with 0xAA and never re-poisons: zero them here
    hipMemsetAsync(out, 0, (size_t)BATCH * DIM * sizeof(float), stream);
    hipMemsetAsync(rs,  0, (size_t)BATCH * sizeof(float), stream);

    dim3 grid(BATCH / ROWS_PER_BLOCK, KPARTS);   // 32 x 16 = 512 WGs
    hashemb_matmul<<<grid, 256, 0, stream>>>(inp, emb, out, rs);

    hashemb_finalize<<<(BATCH * DIM + 255) / 256, 256, 0, stream>>>(out, rs);
}

// Round 2
// 242.368 us; speedup vs baseline: 1.2134x; 1.2134x over previous
//
#include <hip/hip_runtime.h>
#include <hip/hip_bf16.h>

#define BATCH 2048
#define KDIM  100000
#define DIM   64
#define NKB   (KDIM / 32)        // 3125 k-blocks of 32 (exact)
#define KP    32                 // k-partitions
#define ROWS_PER_BLOCK 64        // 4 waves x 16 rows

typedef __attribute__((ext_vector_type(8))) short  short8;
typedef __attribute__((ext_vector_type(4))) float  f32x4;

__device__ __forceinline__ unsigned short f2bf(float f) {
    union { float f; unsigned int u; } v; v.f = f;
    unsigned int u = v.u;
    u += 0x7FFFu + ((u >> 16) & 1u);          // round-to-nearest-even
    return (unsigned short)(u >> 16);
}

// ---- pack emb -> bf16, MFMA-B-fragment order ----
// packedB[((kb*4 + t)*64 + lane)*8 + j] = bf16(emb[kb*32 + (lane>>4)*8 + j][t*16 + (lane&15)])
__global__ __launch_bounds__(256)
void hashemb_pack(const float* __restrict__ emb, unsigned short* __restrict__ pB) {
    const int kb   = blockIdx.x;              // 0..NKB-1
    const int t    = threadIdx.x >> 6;        // 0..3 col-tile
    const int lane = threadIdx.x & 63;
    const int col  = t * 16 + (lane & 15);
    const int krow = kb * 32 + (lane >> 4) * 8;

    short8 w;
    #pragma unroll
    for (int j = 0; j < 8; ++j)
        w[j] = (short)f2bf(emb[(size_t)(krow + j) * DIM + col]);

    *(short8*)&pB[(((size_t)kb * 4 + t) * 64 + lane) * 8] = w;
}

__global__ __launch_bounds__(256, 4)
void hashemb_matmul(const float* __restrict__ inp,
                    const unsigned short* __restrict__ pB,
                    float* __restrict__ out_acc,
                    float* __restrict__ row_sum) {
    const int tid  = threadIdx.x;
    const int lane = tid & 63;
    const int wid  = tid >> 6;                 // wave 0..3
    const int rb   = blockIdx.x;               // row block 0..31
    const int kp   = blockIdx.y;               // k part 0..KP-1

    const int rowbase = rb * ROWS_PER_BLOCK + wid * 16;
    const int arow    = rowbase + (lane & 15);
    const int kgrp    = lane >> 4;             // 0..3

    const float* ap = inp + (size_t)arow * KDIM + kgrp * 8;
    const unsigned short* bp = pB + (size_t)lane * 8;

    f32x4 acc[4];
    #pragma unroll
    for (int t = 0; t < 4; ++t) acc[t] = (f32x4)0.0f;
    float lsum = 0.0f;

    // one compute step: consume (xa,xb) as k-block kb, then prefetch k-block pf into them
    auto step = [&](int kb, f32x4& xa, f32x4& xb, int pf) {
        short8 af;
        #pragma unroll
        for (int j = 0; j < 4; ++j) {
            af[j]     = (short)f2bf(xa[j]);
            af[4 + j] = (short)f2bf(xb[j]);
        }
        lsum += xa[0] + xa[1] + xa[2] + xa[3]
              + xb[0] + xb[1] + xb[2] + xb[3];
        // prefetch next A (HBM) — issued before the B-load/MFMA tail
        xa = *(const f32x4*)(ap + (size_t)pf * 32);
        xb = *(const f32x4*)(ap + (size_t)pf * 32 + 4);
        const unsigned short* b = bp + (size_t)kb * 4 * 512;
        #pragma unroll
        for (int t = 0; t < 4; ++t) {
            const short8 bf = *(const short8*)(b + t * 512);
            acc[t] = __builtin_amdgcn_mfma_f32_16x16x32_bf16(af, bf, acc[t], 0, 0, 0);
        }
    };

    // 2-deep rotating prefetch, named slots (static indexing)
    const int kb0 = kp;
    const int kb1c = (kp + KP < NKB) ? kp + KP : kp;
    f32x4 s0a = *(const f32x4*)(ap + (size_t)kb0 * 32);
    f32x4 s0b = *(const f32x4*)(ap + (size_t)kb0 * 32 + 4);
    f32x4 s1a = *(const f32x4*)(ap + (size_t)kb1c * 32);
    f32x4 s1b = *(const f32x4*)(ap + (size_t)kb1c * 32 + 4);

    for (int kb = kp; kb < NKB; kb += 2 * KP) {
        {
            int pf = kb + 2 * KP; if (pf >= NKB) pf = kb;
            step(kb, s0a, s0b, pf);
        }
        const int kbn = kb + KP;
        if (kbn < NKB) {                       // block-uniform branch
            int pf = kbn + 2 * KP; if (pf >= NKB) pf = kbn;
            step(kbn, s1a, s1b, pf);
        }
    }

    // ---- row-sum partial: reduce over the 4 k-groups ----
    lsum += __shfl_xor(lsum, 16, 64);
    lsum += __shfl_xor(lsum, 32, 64);
    if (lane < 16) atomicAdd(&row_sum[rowbase + lane], lsum);

    // ---- matmul partial: C/D layout col = lane&15, row = (lane>>4)*4 + j ----
    #pragma unroll
    for (int t = 0; t < 4; ++t) {
        const int col = t * 16 + (lane & 15);
        #pragma unroll
        for (int j = 0; j < 4; ++j) {
            const int row = rowbase + kgrp * 4 + j;
            atomicAdd(&out_acc[row * DIM + col], acc[t][j]);
        }
    }
}

__global__ __launch_bounds__(256)
void hashemb_finalize(float* __restrict__ out, const float* __restrict__ row_sum) {
    const int idx = blockIdx.x * blockDim.x + threadIdx.x;
    if (idx < BATCH * DIM) {
        const float s = row_sum[idx >> 6];
        const float o = out[idx];
        out[idx] = (s > 0.0f) ? (o / s) : 0.0f;
    }
}

extern "C" void kernel_launch(void* const* d_in, const int* in_sizes, int n_in,
                              void* d_out, int out_size, void* d_ws, size_t ws_size,
                              hipStream_t stream) {
    const float* inp = (const float*)d_in[0];
    const float* emb = (const float*)d_in[1];
    float* out = (float*)d_out;
    float* rs  = (float*)d_ws;                              // 2048 f32 = 8 KB
    unsigned short* pB = (unsigned short*)((char*)d_ws + 8192);  // 12.8 MB bf16

    // harness poisons d_out/d_ws with 0xAA and never re-poisons: zero/overwrite here
    hipMemsetAsync(out, 0, (size_t)BATCH * DIM * sizeof(float), stream);
    hipMemsetAsync(rs,  0, (size_t)BATCH * sizeof(float), stream);

    hashemb_pack<<<NKB, 256, 0, stream>>>(emb, pB);

    dim3 grid(BATCH / ROWS_PER_BLOCK, KP);                  // 32 x 32 = 1024 WGs
    hashemb_matmul<<<grid, 256, 0, stream>>>(inp, pB, out, rs);

    hashemb_finalize<<<(BATCH * DIM + 255) / 256, 256, 0, stream>>>(out, rs);
}

// Round 4
// 240.407 us; speedup vs baseline: 1.2233x; 1.0082x over previous
//
#include <hip/hip_runtime.h>
#include <hip/hip_bf16.h>

#define BATCH 2048
#define KDIM  100000
#define DIM   64
#define NKB   (KDIM / 32)        // 3125 k-blocks of 32 (exact)
#define KP    32                 // k-partitions (contiguous slabs of 97/98 kb)
#define ROWS_PER_BLOCK 64        // 4 waves x 16 rows

typedef __attribute__((ext_vector_type(8))) short  short8;
typedef __attribute__((ext_vector_type(4))) float  f32x4;

__device__ __forceinline__ unsigned short f2bf(float f) {
    union { float f; unsigned int u; } v; v.f = f;
    unsigned int u = v.u;
    u += 0x7FFFu + ((u >> 16) & 1u);          // round-to-nearest-even
    return (unsigned short)(u >> 16);
}

// ---- pack emb -> bf16 in MFMA-B-fragment order (writes pB only) ----
// packedB[((kb*4 + t)*64 + lane)*8 + j] = bf16(emb[kb*32 + (lane>>4)*8 + j][t*16 + (lane&15)])
__global__ __launch_bounds__(256)
void hashemb_pack(const float* __restrict__ emb, unsigned short* __restrict__ pB) {
    const int kb   = blockIdx.x;              // 0..NKB-1
    const int t    = threadIdx.x >> 6;        // 0..3 col-tile
    const int lane = threadIdx.x & 63;
    const int col  = t * 16 + (lane & 15);
    const int krow = kb * 32 + (lane >> 4) * 8;

    short8 w;
    #pragma unroll
    for (int j = 0; j < 8; ++j)
        w[j] = (short)f2bf(emb[(size_t)(krow + j) * DIM + col]);

    *(short8*)&pB[(((size_t)kb * 4 + t) * 64 + lane) * 8] = w;
}

__global__ __launch_bounds__(256, 4)
void hashemb_matmul(const float* __restrict__ inp,
                    const unsigned short* __restrict__ pB,
                    float* __restrict__ out_acc,
                    float* __restrict__ row_sum) {
    const int tid  = threadIdx.x;
    const int lane = tid & 63;
    const int wid  = tid >> 6;                 // wave 0..3
    const int rb   = blockIdx.x;               // row block 0..31
    const int kp   = blockIdx.y;               // k part 0..KP-1

    const int rowbase = rb * ROWS_PER_BLOCK + wid * 16;
    const int arow    = rowbase + (lane & 15);
    const int kgrp    = lane >> 4;             // 0..3

    // contiguous k-slab for this block
    const int base = NKB / KP;                 // 97
    const int rem  = NKB % KP;                 // 21
    const int cnt  = base + (kp < rem ? 1 : 0);
    const int kb0  = kp * base + (kp < rem ? kp : rem);

    const float* ap = inp + (size_t)arow * KDIM + (size_t)kb0 * 32 + kgrp * 8;
    const unsigned short* bp = pB + ((size_t)kb0 * 4 * 64 + lane) * 8;

    f32x4 acc[4];
    #pragma unroll
    for (int t = 0; t < 4; ++t) acc[t] = (f32x4)0.0f;
    float lsum = 0.0f;

    auto loadA = [&](int idx, f32x4& xa, f32x4& xb) {
        const int c = (idx < cnt) ? idx : cnt - 1;   // clamped redundant reload at tail
        xa = *(const f32x4*)(ap + (size_t)c * 32);
        xb = *(const f32x4*)(ap + (size_t)c * 32 + 4);
    };

    auto consume = [&](int idx, f32x4& xa, f32x4& xb) {
        if (idx < cnt) {                       // block-uniform guard
            short8 af;
            #pragma unroll
            for (int j = 0; j < 4; ++j) {
                af[j]     = (short)f2bf(xa[j]);
                af[4 + j] = (short)f2bf(xb[j]);
            }
            lsum += xa[0] + xa[1] + xa[2] + xa[3]
                  + xb[0] + xb[1] + xb[2] + xb[3];
            const unsigned short* b = bp + (size_t)idx * 2048;
            #pragma unroll
            for (int t = 0; t < 4; ++t) {
                const short8 bf = *(const short8*)(b + t * 512);
                acc[t] = __builtin_amdgcn_mfma_f32_16x16x32_bf16(af, bf, acc[t], 0, 0, 0);
            }
        }
    };

    // batch-refill double buffer: issue 4 k-blocks of A-loads back-to-back
    // (512 B per row per batch -> DRAM page-hit friendly), then consume 4 steps.
    f32x4 a0a, a0b, a1a, a1b, a2a, a2b, a3a, a3b;   // set A
    f32x4 b0a, b0b, b1a, b1b, b2a, b2b, b3a, b3b;   // set B

    loadA(0, a0a, a0b); loadA(1, a1a, a1b);
    loadA(2, a2a, a2b); loadA(3, a3a, a3b);

    for (int g = 0; g < cnt; g += 8) {         // cnt in {97,98}
        loadA(g + 4, b0a, b0b); loadA(g + 5, b1a, b1b);
        loadA(g + 6, b2a, b2b); loadA(g + 7, b3a, b3b);

        consume(g + 0, a0a, a0b); consume(g + 1, a1a, a1b);
        consume(g + 2, a2a, a2b); consume(g + 3, a3a, a3b);

        loadA(g + 8,  a0a, a0b); loadA(g + 9,  a1a, a1b);
        loadA(g + 10, a2a, a2b); loadA(g + 11, a3a, a3b);

        consume(g + 4, b0a, b0b); consume(g + 5, b1a, b1b);
        consume(g + 6, b2a, b2b); consume(g + 7, b3a, b3b);
    }

    // ---- row-sum partial: reduce over the 4 k-groups ----
    lsum += __shfl_xor(lsum, 16, 64);
    lsum += __shfl_xor(lsum, 32, 64);
    if (lane < 16) atomicAdd(&row_sum[rowbase + lane], lsum);

    // ---- matmul partial: C/D layout col = lane&15, row = (lane>>4)*4 + j ----
    #pragma unroll
    for (int t = 0; t < 4; ++t) {
        const int col = t * 16 + (lane & 15);
        #pragma unroll
        for (int j = 0; j < 4; ++j) {
            const int row = rowbase + kgrp * 4 + j;
            atomicAdd(&out_acc[row * DIM + col], acc[t][j]);
        }
    }
}

__global__ __launch_bounds__(256)
void hashemb_finalize(float* __restrict__ out, const float* __restrict__ row_sum) {
    const int idx = blockIdx.x * blockDim.x + threadIdx.x;
    if (idx < BATCH * DIM) {
        const float s = row_sum[idx >> 6];
        const float o = out[idx];
        out[idx] = (s > 0.0f) ? (o / s) : 0.0f;
    }
}

extern "C" void kernel_launch(void* const* d_in, const int* in_sizes, int n_in,
                              void* d_out, int out_size, void* d_ws, size_t ws_size,
                              hipStream_t stream) {
    const float* inp = (const float*)d_in[0];
    const float* emb = (const float*)d_in[1];
    float* out = (float*)d_out;
    float* rs  = (float*)d_ws;                                   // 2048 f32 = 8 KB
    unsigned short* pB = (unsigned short*)((char*)d_ws + 8192);  // 12.8 MB bf16

    // proven-safe init path (round 2): explicit async memsets on the stream
    hipMemsetAsync(out, 0, (size_t)BATCH * DIM * sizeof(float), stream);
    hipMemsetAsync(rs,  0, (size_t)BATCH * sizeof(float), stream);

    hashemb_pack<<<NKB, 256, 0, stream>>>(emb, pB);

    dim3 grid(BATCH / ROWS_PER_BLOCK, KP);                       // 32 x 32 = 1024 WGs
    hashemb_matmul<<<grid, 256, 0, stream>>>(inp, pB, out, rs);

    hashemb_finalize<<<(BATCH * DIM + 255) / 256, 256, 0, stream>>>(out, rs);
}

// Round 5
// 216.932 us; speedup vs baseline: 1.3557x; 1.1082x over previous
//
#include <hip/hip_runtime.h>
#include <hip/hip_bf16.h>

#define BATCH 2048
#define KDIM  100000
#define DIM   64
#define NKB   (KDIM / 32)        // 3125 k-blocks of 32 (exact)
#define KP    64                 // k-partitions (contiguous slabs of 48/49 kb)
#define RPB   128                // rows per WG: 4 waves x 32 rows (M=2 tiles)
#define NRB   (BATCH / RPB)      // 16 row-blocks

typedef __attribute__((ext_vector_type(8))) short  short8;
typedef __attribute__((ext_vector_type(4))) float  f32x4;

__device__ __forceinline__ unsigned short f2bf(float f) {
    union { float f; unsigned int u; } v; v.f = f;
    unsigned int u = v.u;
    u += 0x7FFFu + ((u >> 16) & 1u);          // round-to-nearest-even
    return (unsigned short)(u >> 16);
}

// ---- pack emb -> bf16 in MFMA-B-fragment order ----
// pB[((kb*4 + t)*64 + lane)*8 + j] = bf16(emb[kb*32 + (lane>>4)*8 + j][t*16 + (lane&15)])
__global__ __launch_bounds__(256)
void hashemb_pack(const float* __restrict__ emb, unsigned short* __restrict__ pB) {
    const int kb   = blockIdx.x;              // 0..NKB-1
    const int t    = threadIdx.x >> 6;        // 0..3 col-tile
    const int lane = threadIdx.x & 63;
    const int col  = t * 16 + (lane & 15);
    const int krow = kb * 32 + (lane >> 4) * 8;

    short8 w;
    #pragma unroll
    for (int j = 0; j < 8; ++j)
        w[j] = (short)f2bf(emb[(size_t)(krow + j) * DIM + col]);

    *(short8*)&pB[(((size_t)kb * 4 + t) * 64 + lane) * 8] = w;
}

__global__ __launch_bounds__(256, 4)
void hashemb_matmul(const float* __restrict__ inp,
                    const unsigned short* __restrict__ pB,
                    float* __restrict__ part,     // [KP][BATCH][DIM]
                    float* __restrict__ rsp) {    // [KP][BATCH]
    const int tid  = threadIdx.x;
    const int lane = tid & 63;
    const int wid  = tid >> 6;                 // wave 0..3

    // XCD-aware swizzle: XCD = wg & 7 (round-robin dispatch); give each XCD a
    // contiguous chunk of KP/8 = 8 kp-slabs -> per-XCD B working set ~1.6 MB (L2-fit).
    const int wg  = blockIdx.x;                // 0..1023 (16 rb x 64 kp)
    const int xcd = wg & 7;
    const int pos = wg >> 3;                   // 0..127
    const int kp  = xcd * (KP / 8) + (pos >> 4);
    const int rb  = pos & 15;

    // contiguous k-slab for this block
    const int base = NKB / KP;                 // 48
    const int rem  = NKB % KP;                 // 53
    const int cnt  = base + (kp < rem ? 1 : 0);
    const int kb0  = kp * base + (kp < rem ? kp : rem);

    const int rowbase = rb * RPB + wid * 32;
    const int r0   = rowbase + (lane & 15);
    const int kgrp = lane >> 4;                // 0..3

    const float* ap0 = inp + (size_t)r0 * KDIM + (size_t)kb0 * 32 + kgrp * 8;
    const float* ap1 = ap0 + (size_t)16 * KDIM;                 // row r0+16
    const unsigned short* bp = pB + ((size_t)kb0 * 4 * 64 + lane) * 8;

    f32x4 acc0[4], acc1[4];
    #pragma unroll
    for (int t = 0; t < 4; ++t) { acc0[t] = (f32x4)0.0f; acc1[t] = (f32x4)0.0f; }
    float lsum0 = 0.0f, lsum1 = 0.0f;

    auto loadA = [&](int c, f32x4& xa, f32x4& xb, f32x4& ya, f32x4& yb) {
        const int cc = (c < cnt) ? c : cnt - 1;    // clamped redundant reload at tail
        xa = *(const f32x4*)(ap0 + (size_t)cc * 32);
        xb = *(const f32x4*)(ap0 + (size_t)cc * 32 + 4);
        ya = *(const f32x4*)(ap1 + (size_t)cc * 32);
        yb = *(const f32x4*)(ap1 + (size_t)cc * 32 + 4);
    };

    // consume k-block c from the given regs, then prefetch k-block c+2 into them
    auto step = [&](int c, f32x4& xa, f32x4& xb, f32x4& ya, f32x4& yb) {
        if (c < cnt) {                             // block-uniform guard
            short8 af0, af1;
            #pragma unroll
            for (int j = 0; j < 4; ++j) {
                af0[j] = (short)f2bf(xa[j]);  af0[4 + j] = (short)f2bf(xb[j]);
                af1[j] = (short)f2bf(ya[j]);  af1[4 + j] = (short)f2bf(yb[j]);
            }
            lsum0 += xa[0] + xa[1] + xa[2] + xa[3] + xb[0] + xb[1] + xb[2] + xb[3];
            lsum1 += ya[0] + ya[1] + ya[2] + ya[3] + yb[0] + yb[1] + yb[2] + yb[3];
            loadA(c + 2, xa, xb, ya, yb);          // prefetch before MFMA tail
            const unsigned short* b = bp + (size_t)c * 2048;
            #pragma unroll
            for (int t = 0; t < 4; ++t) {
                const short8 bf = *(const short8*)(b + t * 512);
                acc0[t] = __builtin_amdgcn_mfma_f32_16x16x32_bf16(af0, bf, acc0[t], 0, 0, 0);
                acc1[t] = __builtin_amdgcn_mfma_f32_16x16x32_bf16(af1, bf, acc1[t], 0, 0, 0);
            }
        }
    };

    // 2-set double buffer, named regs (static indexing)
    f32x4 x0a, x0b, y0a, y0b;    // set 0: even k-blocks
    f32x4 x1a, x1b, y1a, y1b;    // set 1: odd  k-blocks
    loadA(0, x0a, x0b, y0a, y0b);
    loadA(1, x1a, x1b, y1a, y1b);

    for (int c = 0; c < cnt; c += 2) {             // cnt in {48,49}
        step(c,     x0a, x0b, y0a, y0b);
        step(c + 1, x1a, x1b, y1a, y1b);
    }

    // ---- row-sum partials: reduce over the 4 k-groups, plain stores ----
    lsum0 += __shfl_xor(lsum0, 16, 64);
    lsum0 += __shfl_xor(lsum0, 32, 64);
    lsum1 += __shfl_xor(lsum1, 16, 64);
    lsum1 += __shfl_xor(lsum1, 32, 64);
    if (lane < 16) {
        rsp[(size_t)kp * BATCH + rowbase + lane]      = lsum0;
        rsp[(size_t)kp * BATCH + rowbase + 16 + lane] = lsum1;
    }

    // ---- matmul partials: C/D layout col = lane&15, row = kgrp*4 + j ----
    float* po = part + (size_t)kp * BATCH * DIM;
    #pragma unroll
    for (int t = 0; t < 4; ++t) {
        const int col = t * 16 + (lane & 15);
        #pragma unroll
        for (int j = 0; j < 4; ++j) {
            const int row = rowbase + kgrp * 4 + j;
            po[(size_t)row * DIM + col]        = acc0[t][j];
            po[(size_t)(row + 16) * DIM + col] = acc1[t][j];
        }
    }
}

// rs[row] = sum_p rsp[p][row]
__global__ __launch_bounds__(256)
void hashemb_rsreduce(const float* __restrict__ rsp, float* __restrict__ rs) {
    const int row = blockIdx.x * 256 + threadIdx.x;   // 8 blocks
    float s = 0.0f;
    #pragma unroll 8
    for (int p = 0; p < KP; ++p) s += rsp[(size_t)p * BATCH + row];
    rs[row] = s;
}

// out[idx] = (s>0) ? sum_p part[p][idx] / s : 0  (vectorized x4)
__global__ __launch_bounds__(256)
void hashemb_finalize(const float* __restrict__ part, const float* __restrict__ rs,
                      float* __restrict__ out) {
    const int i4 = blockIdx.x * 256 + threadIdx.x;    // 128 blocks, 32768 vec4
    const float s = rs[i4 >> 4];                      // 16 vec4 per row
    f32x4 o = (f32x4)0.0f;
    #pragma unroll 8
    for (int p = 0; p < KP; ++p)
        o += *(const f32x4*)(part + (size_t)p * BATCH * DIM + (size_t)i4 * 4);
    const float inv = (s > 0.0f) ? (1.0f / s) : 0.0f;
    o *= inv;
    *(f32x4*)(out + (size_t)i4 * 4) = o;
}

extern "C" void kernel_launch(void* const* d_in, const int* in_sizes, int n_in,
                              void* d_out, int out_size, void* d_ws, size_t ws_size,
                              hipStream_t stream) {
    const float* inp = (const float*)d_in[0];
    const float* emb = (const float*)d_in[1];
    float* out = (float*)d_out;

    // ws layout (all fully overwritten every call -> no init needed):
    //   rs   : 2048 f32                      @ 0        (8 KB)
    //   rsp  : KP x 2048 f32                 @ 8192     (512 KB)
    //   part : KP x 2048 x 64 f32            @ 532480   (33.55 MB)
    //   pB   : NKB x 4 x 64 x 8 bf16         @ 34086912 (12.8 MB)
    float* rs  = (float*)d_ws;
    float* rsp = (float*)((char*)d_ws + 8192);
    float* part = (float*)((char*)d_ws + 532480);
    unsigned short* pB = (unsigned short*)((char*)d_ws + 34086912);

    hashemb_pack<<<NKB, 256, 0, stream>>>(emb, pB);

    hashemb_matmul<<<NRB * KP, 256, 0, stream>>>(inp, pB, part, rsp);

    hashemb_rsreduce<<<BATCH / 256, 256, 0, stream>>>(rsp, rs);

    hashemb_finalize<<<(BATCH * DIM / 4) / 256, 256, 0, stream>>>(part, rs, out);
}

// Round 6
// 212.734 us; speedup vs baseline: 1.3824x; 1.0197x over previous
//
#include <hip/hip_runtime.h>
#include <hip/hip_bf16.h>

#define BATCH 2048
#define KDIM  100000
#define DIM   64
#define NKB   (KDIM / 32)        // 3125 k-blocks of 32 (exact)
#define KP    16                 // k-partitions (slabs of 195/196 kb)
#define NRB   32                 // row-blocks of 64 rows (4 waves x 16)
#define SS    4                  // k-blocks per super-step (512 B per row)
#define NSS   49                 // ceil(196/4) == ceil(195/4): uniform for all kp

typedef __attribute__((ext_vector_type(8))) short  short8;
typedef __attribute__((ext_vector_type(4))) float  f32x4;

__device__ __forceinline__ unsigned short f2bf(float f) {
    union { float f; unsigned int u; } v; v.f = f;
    unsigned int u = v.u;
    u += 0x7FFFu + ((u >> 16) & 1u);          // round-to-nearest-even
    return (unsigned short)(u >> 16);
}

__device__ __forceinline__ void glds16(const float* src, unsigned char* lds) {
    __builtin_amdgcn_global_load_lds(
        (const __attribute__((address_space(1))) void*)src,
        (__attribute__((address_space(3))) void*)lds, 16, 0, 0);
}

// ---- pack emb -> bf16 in MFMA-B-fragment order ----
// pB[((kb*4 + t)*64 + lane)*8 + j] = bf16(emb[kb*32 + (lane>>4)*8 + j][t*16 + (lane&15)])
__global__ __launch_bounds__(256)
void hashemb_pack(const float* __restrict__ emb, unsigned short* __restrict__ pB) {
    const int kb   = blockIdx.x;              // 0..NKB-1
    const int t    = threadIdx.x >> 6;        // 0..3 col-tile
    const int lane = threadIdx.x & 63;
    const int col  = t * 16 + (lane & 15);
    const int krow = kb * 32 + (lane >> 4) * 8;

    short8 w;
    #pragma unroll
    for (int j = 0; j < 8; ++j)
        w[j] = (short)f2bf(emb[(size_t)(krow + j) * DIM + col]);

    *(short8*)&pB[(((size_t)kb * 4 + t) * 64 + lane) * 8] = w;
}

__global__ __launch_bounds__(256, 2)
void hashemb_matmul(const float* __restrict__ inp,
                    const unsigned short* __restrict__ pB,
                    float* __restrict__ part,     // [KP][BATCH][DIM]
                    float* __restrict__ rsp) {    // [KP][BATCH]
    // wave-private A staging: [wave][dbuf][16 rows x 512 B]  (64 KB/WG, 2 WG/CU)
    __shared__ __align__(1024) unsigned char smem[4][2][8192];

    const int tid  = threadIdx.x;
    const int lane = tid & 63;
    const int wid  = tid >> 6;                 // wave 0..3

    // XCD-aware decode: each XCD owns 2 contiguous kp-slabs (B slice ~1.6 MB, L2-fit)
    const int wg  = blockIdx.x;                // 0..511
    const int xcd = wg & 7;
    const int pos = wg >> 3;                   // 0..63
    const int kp  = xcd * 2 + (pos >> 5);      // 0..15
    const int rb  = pos & 31;                  // 0..31

    const int cbase = NKB / KP;                // 195
    const int rem   = NKB % KP;                // 5
    const int cnt   = cbase + (kp < rem ? 1 : 0);
    const int kb0   = kp * cbase + (kp < rem ? kp : rem);
    const int kbEnd = kb0 + cnt;

    const int rowbase = rb * 64 + wid * 16;

    // staging geometry: instr i stages rows {2i, 2i+1}, 512 B each, 1 KB contiguous issue
    const int rsub = lane >> 5;                // which of the 2 rows
    const int gcol = lane & 31;                // dest 16B-granule within row
    // consume geometry (MFMA A-fragment)
    const int frow = lane & 15;                // fragment row
    const int g    = lane >> 4;                // k-group 0..3
    const int sw   = lane & 7;                 // == frow & 7, read-side XOR

    // pre-swizzled global source row pointers (rule #21: linear LDS dest,
    // inverse-swizzled source, swizzled ds_read)
    const float* srcrow[8];
    #pragma unroll
    for (int i = 0; i < 8; ++i) {
        const int r = 2 * i + rsub;
        srcrow[i] = inp + (size_t)(rowbase + r) * KDIM + ((gcol ^ (r & 7)) << 2);
    }

    unsigned char* cur = &smem[wid][0][0];
    unsigned char* nxt = &smem[wid][1][0];

    auto ssStart = [&](int s) {                // clamped super-step base (array-end safe)
        int b = kb0 + s * SS;
        return (b > NKB - SS) ? (NKB - SS) : b;
    };
    auto issue = [&](int base, unsigned char* buf) {
        #pragma unroll
        for (int i = 0; i < 8; ++i)
            glds16(srcrow[i] + (size_t)base * 32, buf + i * 1024);
    };

    f32x4 acc[4];
    #pragma unroll
    for (int t = 0; t < 4; ++t) acc[t] = (f32x4)0.0f;
    float lsum = 0.0f;

    issue(kb0, cur);                           // prologue: 8 glds in flight

    for (int s = 0; s < NSS; ++s) {
        const int base = ssStart(s);
        const int lo   = kb0 + s * SS;

        // 1. B-fragment prefetch for THIS step — issued BEFORE next glds so the
        //    counted vmcnt below retires {glds(s), B} and leaves glds(s+1) in flight
        short8 Br[4][4];
        #pragma unroll
        for (int q = 0; q < SS; ++q) {
            const unsigned short* bq = pB + (size_t)(base + q) * 2048 + (size_t)lane * 8;
            #pragma unroll
            for (int t = 0; t < 4; ++t)
                Br[q][t] = *(const short8*)(bq + t * 512);
        }
        __builtin_amdgcn_sched_barrier(0);

        // 2. stage next super-step into the other half
        if (s + 1 < NSS) {
            issue(ssStart(s + 1), nxt);
            asm volatile("s_waitcnt vmcnt(8)" ::: "memory");   // drain glds(s)+B, keep glds(s+1)
        } else {
            asm volatile("s_waitcnt vmcnt(0)" ::: "memory");
        }
        __builtin_amdgcn_sched_barrier(0);

        // 3. consume current buffer: swizzled ds_read_b128 + convert + MFMA
        #pragma unroll
        for (int q = 0; q < SS; ++q) {
            const int c = base + q;
            if (c >= lo && c < kbEnd) {        // block-uniform
                const int jb = (q << 3) + (g << 1);
                const f32x4 xa = *(const f32x4*)(cur + frow * 512 + (((jb    ) ^ sw) << 4));
                const f32x4 xb = *(const f32x4*)(cur + frow * 512 + (((jb + 1) ^ sw) << 4));
                short8 af;
                #pragma unroll
                for (int j = 0; j < 4; ++j) {
                    af[j]     = (short)f2bf(xa[j]);
                    af[4 + j] = (short)f2bf(xb[j]);
                }
                lsum += xa[0] + xa[1] + xa[2] + xa[3]
                      + xb[0] + xb[1] + xb[2] + xb[3];
                #pragma unroll
                for (int t = 0; t < 4; ++t)
                    acc[t] = __builtin_amdgcn_mfma_f32_16x16x32_bf16(af, Br[q][t], acc[t], 0, 0, 0);
            }
        }

        unsigned char* tmp = cur; cur = nxt; nxt = tmp;
    }

    // ---- row-sum partials: reduce over the 4 k-groups ----
    lsum += __shfl_xor(lsum, 16, 64);
    lsum += __shfl_xor(lsum, 32, 64);
    if (lane < 16) rsp[(size_t)kp * BATCH + rowbase + lane] = lsum;

    // ---- matmul partials: C/D layout col = lane&15, row = (lane>>4)*4 + j ----
    float* po = part + (size_t)kp * BATCH * DIM;
    #pragma unroll
    for (int t = 0; t < 4; ++t) {
        const int col = t * 16 + frow;
        #pragma unroll
        for (int j = 0; j < 4; ++j) {
            const int row = rowbase + g * 4 + j;
            po[(size_t)row * DIM + col] = acc[t][j];
        }
    }
}

// rs[row] = sum_p rsp[p][row]
__global__ __launch_bounds__(256)
void hashemb_rsreduce(const float* __restrict__ rsp, float* __restrict__ rs) {
    const int row = blockIdx.x * 256 + threadIdx.x;   // 8 blocks
    float s = 0.0f;
    #pragma unroll
    for (int p = 0; p < KP; ++p) s += rsp[(size_t)p * BATCH + row];
    rs[row] = s;
}

// out[idx] = (s>0) ? sum_p part[p][idx] / s : 0  (vectorized x4)
__global__ __launch_bounds__(256)
void hashemb_finalize(const float* __restrict__ part, const float* __restrict__ rs,
                      float* __restrict__ out) {
    const int i4 = blockIdx.x * 256 + threadIdx.x;    // 128 blocks, 32768 vec4
    const float s = rs[i4 >> 4];                      // 16 vec4 per row
    f32x4 o = (f32x4)0.0f;
    #pragma unroll
    for (int p = 0; p < KP; ++p)
        o += *(const f32x4*)(part + (size_t)p * BATCH * DIM + (size_t)i4 * 4);
    const float inv = (s > 0.0f) ? (1.0f / s) : 0.0f;
    o *= inv;
    *(f32x4*)(out + (size_t)i4 * 4) = o;
}

extern "C" void kernel_launch(void* const* d_in, const int* in_sizes, int n_in,
                              void* d_out, int out_size, void* d_ws, size_t ws_size,
                              hipStream_t stream) {
    const float* inp = (const float*)d_in[0];
    const float* emb = (const float*)d_in[1];
    float* out = (float*)d_out;

    // ws layout (every slot overwritten every call -> no init/memset needed):
    //   rs   : 2048 f32                 @ 0         (8 KB)
    //   rsp  : KP x 2048 f32            @ 8192      (128 KB)
    //   part : KP x 2048 x 64 f32       @ 139264    (8.39 MB)
    //   pB   : NKB x 4 x 64 x 8 bf16    @ 8527872   (12.8 MB)
    float* rs   = (float*)d_ws;
    float* rsp  = (float*)((char*)d_ws + 8192);
    float* part = (float*)((char*)d_ws + 139264);
    unsigned short* pB = (unsigned short*)((char*)d_ws + 8527872);

    hashemb_pack<<<NKB, 256, 0, stream>>>(emb, pB);

    hashemb_matmul<<<NRB * KP, 256, 0, stream>>>(inp, pB, part, rsp);

    hashemb_rsreduce<<<BATCH / 256, 256, 0, stream>>>(rsp, rs);

    hashemb_finalize<<<(BATCH * DIM / 4) / 256, 256, 0, stream>>>(part, rs, out);
}